// Round 1
// baseline (611.641 us; speedup 1.0000x reference)
//
#include <hip/hip_runtime.h>
#include <hip/hip_fp16.h>

// WindowAttention fused kernel for MI355X (gfx950).
// B=4096 windows, N=49 tokens (pad 64), C=192, H=6, hd=32.
// prep_kernel: fp32->bf16 weights into ws, padded bias table [6][64][64] into ws.
// winattn_kernel: one block per window, 256 threads (4 waves), fully fused
// QKV -> attention (per-head) -> proj with per-head partial-proj accumulation.

typedef short bf16x8 __attribute__((ext_vector_type(8)));
typedef float f32x4 __attribute__((ext_vector_type(4)));

#define MFMA16(a, b, c) __builtin_amdgcn_mfma_f32_16x16x32_bf16((a), (b), (c), 0, 0, 0)

#define DIMC 192
#define NTOK 49

// round-to-nearest-even fp32 -> bf16
__device__ __forceinline__ unsigned short f2bf(float f) {
  unsigned int u = __float_as_uint(f);
  u += 0x7fffu + ((u >> 16) & 1u);
  return (unsigned short)(u >> 16);
}

__global__ void prep_kernel(const float* __restrict__ qkv_w,
                            const float* __restrict__ proj_w,
                            const float* __restrict__ bias_table,
                            const int* __restrict__ rel_idx,
                            unsigned short* __restrict__ qkv_wb,
                            unsigned short* __restrict__ proj_wb,
                            float* __restrict__ biasP) {
  int i = blockIdx.x * 256 + threadIdx.x;
  if (i < 576 * 192) qkv_wb[i] = f2bf(qkv_w[i]);
  if (i < 192 * 192) proj_wb[i] = f2bf(proj_w[i]);
  if (i < 6 * 64 * 64) {
    int h = i >> 12;
    int rr = i & 4095;
    int r = rr >> 6, c = rr & 63;
    float v = 0.f;
    if (r < NTOK && c < NTOK) v = bias_table[rel_idx[r * NTOK + c] * 6 + h];
    biasP[i] = v;
  }
}

__global__ __launch_bounds__(256, 2) void winattn_kernel(
    const float* __restrict__ x,
    const float* __restrict__ mask,
    const float* __restrict__ qkv_b,
    const float* __restrict__ proj_b,
    const unsigned short* __restrict__ qkv_wb,
    const unsigned short* __restrict__ proj_wb,
    const float* __restrict__ biasP,
    float* __restrict__ out) {
  // LDS: 62,976 B total (< 64 KB) -> 2 blocks/CU
  __shared__ unsigned short xb[64 * 200];   // x in bf16, row stride 200
  __shared__ unsigned short Qs[64 * 40];    // per-head Q (scaled), stride 40
  __shared__ unsigned short Ks[64 * 40];    // per-head K, stride 40
  __shared__ unsigned short Vts[32 * 72];   // per-head V^T [d][k], stride 72
  __shared__ unsigned short Pb[4 * 16 * 72];// per-wave P strip, stride 72
  __shared__ unsigned short Ob[64 * 40];    // per-head attention out, stride 40
  __shared__ __half maskS[64 * 64];         // padded mask (cols>=49 -> -3e4)

  const int tid = threadIdx.x;
  const int b = blockIdx.x;
  const int widx = b & 63;          // window index for mask: b % 64
  const int lane = tid & 63;
  const int wv = tid >> 6;          // wave 0..3
  const int lq = lane >> 4;         // quad 0..3
  const int ln = lane & 15;

  // ---------------- stage x (bf16, zero rows >=49) + mask (fp16, padded)
  {
    const float4* xp = (const float4*)(x + (size_t)b * (NTOK * DIMC));
    for (int i = tid; i < NTOK * DIMC / 4; i += 256) {
      float4 v = xp[i];
      int fl = i * 4;
      int r = fl / DIMC;
      int c = fl - r * DIMC;
      unsigned int lo = (unsigned int)f2bf(v.x) | ((unsigned int)f2bf(v.y) << 16);
      unsigned int hi = (unsigned int)f2bf(v.z) | ((unsigned int)f2bf(v.w) << 16);
      *(uint2*)(&xb[r * 200 + c]) = make_uint2(lo, hi);
    }
    for (int i = tid; i < 15 * 200 / 2; i += 256)
      ((unsigned int*)(&xb[49 * 200]))[i] = 0u;
    const float* mp = mask + (size_t)widx * (NTOK * NTOK);
    for (int i = tid; i < 64 * 64; i += 256) {
      int r = i >> 6, c = i & 63;
      float v = (c >= NTOK) ? -30000.f : ((r >= NTOK) ? 0.f : mp[r * NTOK + c]);
      maskS[i] = __float2half(v);
    }
  }

  // persistent proj accumulators: wave owns out-cols [wv*48 .. wv*48+47] (3 ntiles)
  f32x4 pacc[4][3];
  for (int nti = 0; nti < 3; ++nti) {
    float pbv = proj_b[(wv * 3 + nti) * 16 + ln];
    for (int mt = 0; mt < 4; ++mt) pacc[mt][nti] = (f32x4){pbv, pbv, pbv, pbv};
  }
  __syncthreads();

  const float scale = 0.17677669529663687f;  // 1/sqrt(32)

  for (int h = 0; h < 6; ++h) {
    // ---------------- per-head QKV GEMM: 6 local ntiles x 4 mtiles = 24 pairs,
    // this wave takes 6 (as 3 duos for ILP). K=192 -> 6 ksteps of 32.
    for (int tt = 0; tt < 6; tt += 2) {
      int t0 = wv * 6 + tt;
      int t1 = t0 + 1;
      int nt0 = t0 >> 2, mt0 = t0 & 3;
      int nt1 = t1 >> 2, mt1 = t1 & 3;
      int oc0 = (nt0 >> 1) * DIMC + h * 32 + (nt0 & 1) * 16 + ln;  // weight row / out col
      int oc1 = (nt1 >> 1) * DIMC + h * 32 + (nt1 & 1) * 16 + ln;
      const unsigned short* w0p = qkv_wb + (size_t)oc0 * DIMC + lq * 8;
      const unsigned short* w1p = qkv_wb + (size_t)oc1 * DIMC + lq * 8;
      bf16x8 w0[6], w1[6];
      for (int ks = 0; ks < 6; ++ks) {
        w0[ks] = *(const bf16x8*)(w0p + ks * 32);
        w1[ks] = *(const bf16x8*)(w1p + ks * 32);
      }
      float b0 = qkv_b[oc0], b1 = qkv_b[oc1];
      f32x4 acc0 = (f32x4){b0, b0, b0, b0};
      f32x4 acc1 = (f32x4){b1, b1, b1, b1};
      const unsigned short* a0p = &xb[(mt0 * 16 + ln) * 200 + lq * 8];
      const unsigned short* a1p = &xb[(mt1 * 16 + ln) * 200 + lq * 8];
      for (int ks = 0; ks < 6; ++ks) {
        bf16x8 a0 = *(const bf16x8*)(a0p + ks * 32);
        bf16x8 a1 = *(const bf16x8*)(a1p + ks * 32);
        acc0 = MFMA16(a0, w0[ks], acc0);
        acc1 = MFMA16(a1, w1[ks], acc1);
      }
      // epilogue: route tile to Q (scaled) / K / V^T LDS. C-layout:
      // row = mt*16 + lq*4 + r, col(within head-part) = (nt&1)*16 + ln
      {
        int which = nt0 >> 1, db = (nt0 & 1) * 16 + ln, row0 = mt0 * 16 + lq * 4;
        if (which == 0) {
          for (int r = 0; r < 4; ++r) Qs[(row0 + r) * 40 + db] = f2bf(acc0[r] * scale);
        } else if (which == 1) {
          for (int r = 0; r < 4; ++r) Ks[(row0 + r) * 40 + db] = f2bf(acc0[r]);
        } else {
          unsigned int lo = (unsigned int)f2bf(acc0[0]) | ((unsigned int)f2bf(acc0[1]) << 16);
          unsigned int hi = (unsigned int)f2bf(acc0[2]) | ((unsigned int)f2bf(acc0[3]) << 16);
          *(uint2*)(&Vts[db * 72 + row0]) = make_uint2(lo, hi);
        }
      }
      {
        int which = nt1 >> 1, db = (nt1 & 1) * 16 + ln, row0 = mt1 * 16 + lq * 4;
        if (which == 0) {
          for (int r = 0; r < 4; ++r) Qs[(row0 + r) * 40 + db] = f2bf(acc1[r] * scale);
        } else if (which == 1) {
          for (int r = 0; r < 4; ++r) Ks[(row0 + r) * 40 + db] = f2bf(acc1[r]);
        } else {
          unsigned int lo = (unsigned int)f2bf(acc1[0]) | ((unsigned int)f2bf(acc1[1]) << 16);
          unsigned int hi = (unsigned int)f2bf(acc1[2]) | ((unsigned int)f2bf(acc1[3]) << 16);
          *(uint2*)(&Vts[db * 72 + row0]) = make_uint2(lo, hi);
        }
      }
    }
    __syncthreads();

    // ---------------- attention: wave owns query strip mt = wv (16 rows)
    {
      const int mt = wv;
      bf16x8 kf[4], vf0[2], vf1[2];
      for (int nt = 0; nt < 4; ++nt)
        kf[nt] = *(const bf16x8*)&Ks[(nt * 16 + ln) * 40 + lq * 8];
      for (int nv = 0; nv < 2; ++nv) {
        vf0[nv] = *(const bf16x8*)&Vts[(nv * 16 + ln) * 72 + lq * 8];        // keys 0..31
        vf1[nv] = *(const bf16x8*)&Vts[(nv * 16 + ln) * 72 + 32 + lq * 8];   // keys 32..63
      }
      bf16x8 qf = *(const bf16x8*)&Qs[(mt * 16 + ln) * 40 + lq * 8];
      f32x4 sv[4];
      for (int nt = 0; nt < 4; ++nt)
        sv[nt] = MFMA16(qf, kf[nt], ((f32x4){0.f, 0.f, 0.f, 0.f}));

      int row0 = mt * 16 + lq * 4;
      const float* bp = biasP + ((size_t)h * 64 + row0) * 64;
      float tt[4][4];
      for (int nt = 0; nt < 4; ++nt) {
        int col = nt * 16 + ln;
        for (int r = 0; r < 4; ++r)
          tt[nt][r] = sv[nt][r] + bp[r * 64 + col] + __half2float(maskS[(row0 + r) * 64 + col]);
      }
      // row softmax: row lives in 16 lanes sharing lq (xor masks 1,2,4,8)
      float pinv[4];
      for (int r = 0; r < 4; ++r) {
        float m = fmaxf(fmaxf(tt[0][r], tt[1][r]), fmaxf(tt[2][r], tt[3][r]));
        m = fmaxf(m, __shfl_xor(m, 1, 64));
        m = fmaxf(m, __shfl_xor(m, 2, 64));
        m = fmaxf(m, __shfl_xor(m, 4, 64));
        m = fmaxf(m, __shfl_xor(m, 8, 64));
        float sum = 0.f;
        for (int nt = 0; nt < 4; ++nt) {
          float e = __expf(tt[nt][r] - m);
          tt[nt][r] = e;
          sum += e;
        }
        sum += __shfl_xor(sum, 1, 64);
        sum += __shfl_xor(sum, 2, 64);
        sum += __shfl_xor(sum, 4, 64);
        sum += __shfl_xor(sum, 8, 64);
        pinv[r] = 1.f / sum;
      }
      // P strip -> LDS (C-layout -> A-layout round trip), bf16
      unsigned short* Pw = &Pb[wv * 16 * 72];
      for (int nt = 0; nt < 4; ++nt) {
        int col = nt * 16 + ln;
        for (int r = 0; r < 4; ++r) Pw[(lq * 4 + r) * 72 + col] = f2bf(tt[nt][r]);
      }
      // PV: A = P strip (m=ln, k=lq*8+j), B = V^T
      bf16x8 pa0 = *(const bf16x8*)&Pw[ln * 72 + lq * 8];
      bf16x8 pa1 = *(const bf16x8*)&Pw[ln * 72 + 32 + lq * 8];
      f32x4 o0 = (f32x4){0.f, 0.f, 0.f, 0.f};
      f32x4 o1 = (f32x4){0.f, 0.f, 0.f, 0.f};
      o0 = MFMA16(pa0, vf0[0], o0);
      o0 = MFMA16(pa1, vf1[0], o0);
      o1 = MFMA16(pa0, vf0[1], o1);
      o1 = MFMA16(pa1, vf1[1], o1);
      // normalize rows, write Ob (rows of o match pinv rows: lq*4+r)
      for (int r = 0; r < 4; ++r) {
        int row = row0 + r;
        Ob[row * 40 + ln] = f2bf(o0[r] * pinv[r]);
        Ob[row * 40 + 16 + ln] = f2bf(o1[r] * pinv[r]);
      }
    }
    __syncthreads();

    // ---------------- partial proj: K=32 slice for this head, accumulate
    {
      bf16x8 oa[4];
      for (int mt = 0; mt < 4; ++mt)
        oa[mt] = *(const bf16x8*)&Ob[(mt * 16 + ln) * 40 + lq * 8];
      for (int nti = 0; nti < 3; ++nti) {
        int o = (wv * 3 + nti) * 16 + ln;
        bf16x8 w = *(const bf16x8*)(proj_wb + (size_t)o * DIMC + h * 32 + lq * 8);
        for (int mt = 0; mt < 4; ++mt)
          pacc[mt][nti] = MFMA16(oa[mt], w, pacc[mt][nti]);
      }
    }
    __syncthreads();  // Ob / Qs / Ks / Vts reused next head
  }

  // ---------------- store output (fp32), rows < 49 only
  {
    float* outp = out + (size_t)b * (NTOK * DIMC);
    for (int nti = 0; nti < 3; ++nti) {
      int col = (wv * 3 + nti) * 16 + ln;
      for (int mt = 0; mt < 4; ++mt) {
        int row0 = mt * 16 + lq * 4;
        for (int r = 0; r < 4; ++r) {
          int row = row0 + r;
          if (row < NTOK) outp[row * DIMC + col] = pacc[mt][nti][r];
        }
      }
    }
  }
}

extern "C" void kernel_launch(void* const* d_in, const int* in_sizes, int n_in,
                              void* d_out, int out_size, void* d_ws, size_t ws_size,
                              hipStream_t stream) {
  const float* x = (const float*)d_in[0];
  const float* mask = (const float*)d_in[1];
  const float* qkv_w = (const float*)d_in[2];
  const float* qkv_b = (const float*)d_in[3];
  const float* proj_w = (const float*)d_in[4];
  const float* proj_b = (const float*)d_in[5];
  const float* bias_table = (const float*)d_in[6];
  const int* rel_idx = (const int*)d_in[7];

  unsigned short* qkv_wb = (unsigned short*)d_ws;                 // 576*192 bf16
  unsigned short* proj_wb = qkv_wb + 576 * 192;                   // 192*192 bf16
  float* biasP = (float*)(proj_wb + 192 * 192);                   // 6*64*64 fp32

  prep_kernel<<<432, 256, 0, stream>>>(qkv_w, proj_w, bias_table, rel_idx,
                                       qkv_wb, proj_wb, biasP);
  winattn_kernel<<<4096, 256, 0, stream>>>(x, mask, qkv_b, proj_b,
                                           qkv_wb, proj_wb, biasP,
                                           (float*)d_out);
}